// Round 1
// baseline (748.442 us; speedup 1.0000x reference)
//
#include <hip/hip_runtime.h>

typedef __attribute__((ext_vector_type(8))) short short8;   // 8 bf16 in 4 VGPRs
typedef __attribute__((ext_vector_type(4))) float f32x4;
typedef unsigned short u16;

#define DEVI __device__ __forceinline__

DEVI u16 f2bf(float f) {
  unsigned u = __float_as_uint(f);
  unsigned r = (u + 0x7fffu + ((u >> 16) & 1u)) >> 16;   // RNE
  return (u16)r;
}

DEVI void gl2lds16(const void* g, void* l) {
  __builtin_amdgcn_global_load_lds((const __attribute__((address_space(1))) void*)g,
                                   (__attribute__((address_space(3))) void*)l, 16, 0, 0);
}

// stage bf16 tile ROWS x BKE (row-major, ld elems) into linear LDS via global_load_lds
template<int ROWS, int BKE>
DEVI void stage_bf16(const u16* __restrict__ g, int ld, u16* lds, int tid) {
  constexpr int CPR = BKE / 8;          // 16B chunks per row
  constexpr int CH  = ROWS * CPR;
  const int wave = tid >> 6, lane = tid & 63;
#pragma unroll
  for (int i = 0; i < CH / 256; i++) {
    int c = (i * 4 + wave) * 64 + lane;
    int row = c / CPR;
    int colb = (c % CPR) * 16;
    gl2lds16((const char*)g + (long)row * ld * 2 + colb, (char*)lds + (long)c * 16);
  }
}

// stage fp32 tile ROWS x 32 -> bf16 LDS (reg-staged convert)
template<int ROWS>
DEVI void stage_f32_32(const float* __restrict__ g, int ld, u16* lds, int tid) {
  constexpr int Q4 = ROWS * 8;          // 8 float4 per row
#pragma unroll
  for (int i = 0; i < Q4 / 256; i++) {
    int q = i * 256 + tid;
    int row = q >> 3, c4 = q & 7;
    float4 v = *(const float4*)(g + (long)row * ld + c4 * 4);
    ushort4 h;
    h.x = f2bf(v.x); h.y = f2bf(v.y); h.z = f2bf(v.z); h.w = f2bf(v.w);
    *(ushort4*)(lds + row * 32 + c4 * 4) = h;   // ds_write_b64
  }
}

// one K=32 MFMA step on LDS tiles A[*][BKE], B[*][BKE]; wave tile = 64 x (FN*16)
template<int FM, int FN, int BKE>
DEVI void kstep(const u16* Alds, const u16* Blds, int lane, int wr, int wc, int kk,
                f32x4 (*acc)[FN]) {
  const int ro = lane & 15, ko = kk + (lane >> 4) * 8;
  short8 a[FM], b[FN];
#pragma unroll
  for (int m = 0; m < FM; m++) a[m] = *(const short8*)(Alds + (wr + m * 16 + ro) * BKE + ko);
#pragma unroll
  for (int n = 0; n < FN; n++) b[n] = *(const short8*)(Blds + (wc + n * 16 + ro) * BKE + ko);
#pragma unroll
  for (int m = 0; m < FM; m++)
#pragma unroll
    for (int n = 0; n < FN; n++)
      acc[m][n] = __builtin_amdgcn_mfma_f32_16x16x32_bf16(a[m], b[n], acc[m][n], 0, 0, 0);
}

// ---- projection: Y[s,f] = sum_e X[s,e] W[f,e] + bias[f]; out bf16 (B,H,S,D) ----
__global__ __launch_bounds__(256) void proj_kernel(const float* __restrict__ X,
                                                   const float* __restrict__ W,
                                                   const float* __restrict__ bias,
                                                   u16* __restrict__ Out) {
  __shared__ u16 Alds[128 * 32];
  __shared__ u16 Blds[128 * 32];
  const int tid = threadIdx.x, lane = tid & 63, w = tid >> 6;
  const int wr = (w >> 1) * 64, wc = (w & 1) * 64;
  const long rowB = (long)blockIdx.y * 128;
  const int colB = blockIdx.x * 128;
  f32x4 acc[4][4] = {};
  for (int k0 = 0; k0 < 1024; k0 += 32) {
    stage_f32_32<128>(X + rowB * 1024 + k0, 1024, Alds, tid);
    stage_f32_32<128>(W + (long)colB * 1024 + k0, 1024, Blds, tid);
    __syncthreads();
    kstep<4, 4, 32>(Alds, Blds, lane, wr, wc, 0, acc);
    __syncthreads();
  }
  const int ro = (lane >> 4) * 4, co = lane & 15;
#pragma unroll
  for (int n = 0; n < 4; n++) {
    const int col = colB + wc + n * 16 + co;
    const float bv = bias[col];
    const int h = col >> 6, d = col & 63;
#pragma unroll
    for (int m = 0; m < 4; m++)
#pragma unroll
      for (int j = 0; j < 4; j++) {
        long r = rowB + wr + m * 16 + ro + j;
        long bq = r >> 10, s = r & 1023;
        Out[(((bq * 16 + h) * 1024 + s) << 6) + d] = f2bf(acc[m][n][j] + bv);
      }
  }
}

// ---- V transpose: (bh, s, d) -> (bh, d, s) ----
__global__ __launch_bounds__(256) void vtrans_kernel(const u16* __restrict__ V,
                                                     u16* __restrict__ Vt) {
  __shared__ u16 t[64][72];
  const int tid = threadIdx.x;
  const int bh = blockIdx.z;
  const int sB = blockIdx.x * 64;
  const u16* src = V + (long)bh * 65536 + (long)sB * 64;
#pragma unroll
  for (int i = 0; i < 4; i++) {
    int idx = i * 256 + tid;
    int r = idx >> 4, c4 = idx & 15;
    ushort4 v = *(const ushort4*)(src + r * 64 + c4 * 4);
    *(ushort4*)&t[r][c4 * 4] = v;
  }
  __syncthreads();
  u16* dst = Vt + (long)bh * 65536 + sB;
#pragma unroll
  for (int i = 0; i < 4; i++) {
    int idx = i * 256 + tid;
    int d = idx >> 4, s4 = idx & 15;
    ushort4 v;
    v.x = t[s4 * 4 + 0][d]; v.y = t[s4 * 4 + 1][d];
    v.z = t[s4 * 4 + 2][d]; v.w = t[s4 * 4 + 3][d];
    *(ushort4*)(dst + (long)d * 1024 + s4 * 4) = v;
  }
}

// ---- scores: S[q,k] = 0.125 * sum_d Q[q,d] K[k,d]; fp32 out to d_out ----
__global__ __launch_bounds__(256) void score_kernel(const u16* __restrict__ Q,
                                                    const u16* __restrict__ Km,
                                                    float* __restrict__ attn) {
  __shared__ u16 Alds[128 * 64];
  __shared__ u16 Blds[128 * 64];
  const int tid = threadIdx.x, lane = tid & 63, w = tid >> 6;
  const int wr = (w >> 1) * 64, wc = (w & 1) * 64;
  const int z = blockIdx.z;
  const u16* Qb = Q + (long)z * 65536;
  const u16* Kb = Km + (long)z * 65536;
  const int rowB = blockIdx.y * 128, colB = blockIdx.x * 128;
  stage_bf16<128, 64>(Qb + rowB * 64, 64, Alds, tid);
  stage_bf16<128, 64>(Kb + colB * 64, 64, Blds, tid);
  f32x4 acc[4][4] = {};
  __syncthreads();
  kstep<4, 4, 64>(Alds, Blds, lane, wr, wc, 0, acc);
  kstep<4, 4, 64>(Alds, Blds, lane, wr, wc, 32, acc);
  const int ro = (lane >> 4) * 4, co = lane & 15;
  float* ab = attn + (long)z * 1048576;
#pragma unroll
  for (int m = 0; m < 4; m++)
#pragma unroll
    for (int j = 0; j < 4; j++) {
      long r = rowB + wr + m * 16 + ro + j;
      float* rowp = ab + r * 1024 + colB + wc;
#pragma unroll
      for (int n = 0; n < 4; n++) rowp[n * 16 + co] = 0.125f * acc[m][n][j];
    }
}

// ---- softmax in place over rows of 1024 ----
__global__ __launch_bounds__(256) void softmax_kernel(float* __restrict__ attn) {
  const long row = blockIdx.x;
  float4* p = (float4*)(attn + (row << 10));
  const int tid = threadIdx.x, lane = tid & 63, w = tid >> 6;
  float4 v = p[tid];
  float m = fmaxf(fmaxf(v.x, v.y), fmaxf(v.z, v.w));
#pragma unroll
  for (int o = 32; o > 0; o >>= 1) m = fmaxf(m, __shfl_xor(m, o, 64));
  __shared__ float redm[4], reds[4];
  if (lane == 0) redm[w] = m;
  __syncthreads();
  m = fmaxf(fmaxf(redm[0], redm[1]), fmaxf(redm[2], redm[3]));
  v.x = __expf(v.x - m); v.y = __expf(v.y - m);
  v.z = __expf(v.z - m); v.w = __expf(v.w - m);
  float s = v.x + v.y + v.z + v.w;
#pragma unroll
  for (int o = 32; o > 0; o >>= 1) s += __shfl_xor(s, o, 64);
  if (lane == 0) reds[w] = s;
  __syncthreads();
  s = reds[0] + reds[1] + reds[2] + reds[3];
  const float inv = 1.0f / s;
  v.x *= inv; v.y *= inv; v.z *= inv; v.w *= inv;
  p[tid] = v;
}

// ---- context: C[q,d] = sum_k P[q,k] Vt[d,k]; P fp32 from d_out; out bf16 (B,S,E) ----
__global__ __launch_bounds__(256) void ctx_kernel(const float* __restrict__ attn,
                                                  const u16* __restrict__ Vt,
                                                  u16* __restrict__ Ctx) {
  __shared__ u16 Alds[128 * 32];
  __shared__ u16 Blds[64 * 32];
  const int tid = threadIdx.x, lane = tid & 63, w = tid >> 6;
  const int wr = (w >> 1) * 64, wc = (w & 1) * 32;
  const int z = blockIdx.z, b = z >> 4, h = z & 15;
  const float* Ab = attn + ((long)z << 20);
  const u16* Bb = Vt + (long)z * 65536;
  const long rowB = (long)blockIdx.x * 128;
  f32x4 acc[4][2] = {};
  for (int k0 = 0; k0 < 1024; k0 += 32) {
    stage_f32_32<128>(Ab + rowB * 1024 + k0, 1024, Alds, tid);
    stage_bf16<64, 32>(Bb + k0, 1024, Blds, tid);
    __syncthreads();
    kstep<4, 2, 32>(Alds, Blds, lane, wr, wc, 0, acc);
    __syncthreads();
  }
  const int ro = (lane >> 4) * 4, co = lane & 15;
  u16* cb = Ctx + ((long)b << 20) + h * 64;
#pragma unroll
  for (int m = 0; m < 4; m++)
#pragma unroll
    for (int j = 0; j < 4; j++) {
      long q = rowB + wr + m * 16 + ro + j;
#pragma unroll
      for (int n = 0; n < 2; n++)
        cb[(q << 10) + wc + n * 16 + co] = f2bf(acc[m][n][j]);
    }
}

// ---- out projection: O[s,f] = sum_e Ctx[s,e] W[f,e] + bias[f]; fp32 to d_out ----
__global__ __launch_bounds__(256) void out_kernel(const u16* __restrict__ Ctx,
                                                  const float* __restrict__ W,
                                                  const float* __restrict__ bias,
                                                  float* __restrict__ Out) {
  __shared__ u16 Alds[128 * 32];
  __shared__ u16 Blds[128 * 32];
  const int tid = threadIdx.x, lane = tid & 63, w = tid >> 6;
  const int wr = (w >> 1) * 64, wc = (w & 1) * 64;
  const long rowB = (long)blockIdx.y * 128;
  const int colB = blockIdx.x * 128;
  f32x4 acc[4][4] = {};
  for (int k0 = 0; k0 < 1024; k0 += 32) {
    stage_bf16<128, 32>(Ctx + rowB * 1024 + k0, 1024, Alds, tid);
    stage_f32_32<128>(W + (long)colB * 1024 + k0, 1024, Blds, tid);
    __syncthreads();
    kstep<4, 4, 32>(Alds, Blds, lane, wr, wc, 0, acc);
    __syncthreads();
  }
  const int ro = (lane >> 4) * 4, co = lane & 15;
#pragma unroll
  for (int n = 0; n < 4; n++) {
    const int col = colB + wc + n * 16 + co;
    const float bv = bias[col];
#pragma unroll
    for (int m = 0; m < 4; m++)
#pragma unroll
      for (int j = 0; j < 4; j++) {
        long r = rowB + wr + m * 16 + ro + j;
        Out[r * 1024 + col] = acc[m][n][j] + bv;
      }
  }
}

extern "C" void kernel_launch(void* const* d_in, const int* in_sizes, int n_in,
                              void* d_out, int out_size, void* d_ws, size_t ws_size,
                              hipStream_t stream) {
  const float* query = (const float*)d_in[0];
  const float* key   = (const float*)d_in[1];
  const float* value = (const float*)d_in[2];
  const float* q_w   = (const float*)d_in[3];
  const float* q_b   = (const float*)d_in[4];
  const float* k_w   = (const float*)d_in[5];
  const float* k_b   = (const float*)d_in[6];
  const float* v_w   = (const float*)d_in[7];
  const float* v_b   = (const float*)d_in[8];
  const float* out_w = (const float*)d_in[9];
  const float* out_b = (const float*)d_in[10];

  char* ws = (char*)d_ws;
  u16* Qp  = (u16*)(ws);                   // (B,H,S,D) bf16, 16 MB
  u16* Kp  = (u16*)(ws + 16777216L);       // 16 MB
  u16* Vp  = (u16*)(ws + 2 * 16777216L);   // 16 MB
  u16* Vt  = (u16*)(ws + 3 * 16777216L);   // (B,H,D,S) 16 MB
  u16* Ctx = (u16*)(ws + 4 * 16777216L);   // (B,S,E) 16 MB  -> total 80 MB

  float* attn = (float*)d_out;                       // [8,16,1024,1024]
  float* outp = (float*)d_out + 134217728L;          // [8,1024,1024]

  dim3 blk(256);
  proj_kernel<<<dim3(8, 64), blk, 0, stream>>>(query, q_w, q_b, Qp);
  proj_kernel<<<dim3(8, 64), blk, 0, stream>>>(key, k_w, k_b, Kp);
  proj_kernel<<<dim3(8, 64), blk, 0, stream>>>(value, v_w, v_b, Vp);
  vtrans_kernel<<<dim3(16, 1, 128), blk, 0, stream>>>(Vp, Vt);
  score_kernel<<<dim3(8, 8, 128), blk, 0, stream>>>(Qp, Kp, attn);
  softmax_kernel<<<dim3(131072), blk, 0, stream>>>(attn);
  ctx_kernel<<<dim3(8, 1, 128), blk, 0, stream>>>(attn, Vt, Ctx);
  out_kernel<<<dim3(8, 64), blk, 0, stream>>>(Ctx, out_w, out_b, outp);
}

// Round 2
// 555.730 us; speedup vs baseline: 1.3468x; 1.3468x over previous
//
#include <hip/hip_runtime.h>

typedef __attribute__((ext_vector_type(8))) short short8;   // 8 bf16 in 4 VGPRs
typedef __attribute__((ext_vector_type(4))) float f32x4;
typedef unsigned short u16;

#define DEVI __device__ __forceinline__

DEVI u16 f2bf(float f) {
  unsigned u = __float_as_uint(f);
  unsigned r = (u + 0x7fffu + ((u >> 16) & 1u)) >> 16;   // RNE
  return (u16)r;
}

DEVI void gl2lds16(const void* g, void* l) {
  __builtin_amdgcn_global_load_lds((const __attribute__((address_space(1))) void*)g,
                                   (__attribute__((address_space(3))) void*)l, 16, 0, 0);
}

// stage bf16 tile ROWS x BKE (row-major, ld elems) into linear LDS via global_load_lds
template<int ROWS, int BKE>
DEVI void stage_bf16(const u16* __restrict__ g, int ld, u16* lds, int tid) {
  constexpr int CPR = BKE / 8;          // 16B chunks per row
  constexpr int CH  = ROWS * CPR;
  const int wave = tid >> 6, lane = tid & 63;
#pragma unroll
  for (int i = 0; i < CH / 256; i++) {
    int c = (i * 4 + wave) * 64 + lane;
    int row = c / CPR;
    int colb = (c % CPR) * 16;
    gl2lds16((const char*)g + (long)row * ld * 2 + colb, (char*)lds + (long)c * 16);
  }
}

// stage fp32 tile ROWS x BKE -> bf16 LDS (reg-staged convert)
template<int ROWS, int BKE>
DEVI void stage_f32(const float* __restrict__ g, int ld, u16* lds, int tid) {
  constexpr int QPR = BKE / 4;
  constexpr int Q4 = ROWS * QPR;
#pragma unroll
  for (int i = 0; i < Q4 / 256; i++) {
    int q = i * 256 + tid;
    int row = q / QPR, c4 = q % QPR;
    float4 v = *(const float4*)(g + (long)row * ld + c4 * 4);
    ushort4 h;
    h.x = f2bf(v.x); h.y = f2bf(v.y); h.z = f2bf(v.z); h.w = f2bf(v.w);
    *(ushort4*)(lds + row * BKE + c4 * 4) = h;   // ds_write_b64
  }
}

// one K=32 MFMA step on LDS tiles A[*][BKE], B[*][BKE]; wave tile = (FM*16) x (FN*16)
template<int FM, int FN, int BKE>
DEVI void kstep(const u16* Alds, const u16* Blds, int lane, int wr, int wc, int kk,
                f32x4 (*acc)[FN]) {
  const int ro = lane & 15, ko = kk + (lane >> 4) * 8;
  short8 a[FM], b[FN];
#pragma unroll
  for (int m = 0; m < FM; m++) a[m] = *(const short8*)(Alds + (wr + m * 16 + ro) * BKE + ko);
#pragma unroll
  for (int n = 0; n < FN; n++) b[n] = *(const short8*)(Blds + (wc + n * 16 + ro) * BKE + ko);
#pragma unroll
  for (int m = 0; m < FM; m++)
#pragma unroll
    for (int n = 0; n < FN; n++)
      acc[m][n] = __builtin_amdgcn_mfma_f32_16x16x32_bf16(a[m], b[n], acc[m][n], 0, 0, 0);
}

// ---- fp32 -> bf16 conversion for up to 7 tensors ----
struct CvtArgs {
  const float* s[7];
  u16* d[7];
  int n8[7];
};

__global__ __launch_bounds__(256) void cvt_all(CvtArgs a) {
  const int t = blockIdx.y;
  const int n = a.n8[t];
  const float* __restrict__ s = a.s[t];
  u16* __restrict__ d = a.d[t];
  for (long i = blockIdx.x * 256 + threadIdx.x; i < n; i += (long)gridDim.x * 256) {
    float4 v0 = ((const float4*)s)[2 * i];
    float4 v1 = ((const float4*)s)[2 * i + 1];
    ushort4 h0, h1;
    h0.x = f2bf(v0.x); h0.y = f2bf(v0.y); h0.z = f2bf(v0.z); h0.w = f2bf(v0.w);
    h1.x = f2bf(v1.x); h1.y = f2bf(v1.y); h1.z = f2bf(v1.z); h1.w = f2bf(v1.w);
    ((ushort4*)d)[2 * i] = h0;
    ((ushort4*)d)[2 * i + 1] = h1;
  }
}

// ---- projection (all-bf16): Y[s,f] = sum_e X[s,e] W[f,e] + bias[f]; out bf16 (B,H,S,D) ----
__global__ __launch_bounds__(256) void projb_kernel(const u16* __restrict__ X,
                                                    const u16* __restrict__ W,
                                                    const float* __restrict__ bias,
                                                    u16* __restrict__ Out) {
  __shared__ u16 Alds[128 * 64];
  __shared__ u16 Blds[128 * 64];
  const int tid = threadIdx.x, lane = tid & 63, w = tid >> 6;
  const int wr = (w >> 1) * 64, wc = (w & 1) * 64;
  const long rowB = (long)blockIdx.y * 128;
  const int colB = blockIdx.x * 128;
  f32x4 acc[4][4] = {};
  for (int k0 = 0; k0 < 1024; k0 += 64) {
    stage_bf16<128, 64>(X + rowB * 1024 + k0, 1024, Alds, tid);
    stage_bf16<128, 64>(W + (long)colB * 1024 + k0, 1024, Blds, tid);
    __syncthreads();
    kstep<4, 4, 64>(Alds, Blds, lane, wr, wc, 0, acc);
    kstep<4, 4, 64>(Alds, Blds, lane, wr, wc, 32, acc);
    __syncthreads();
  }
  const int ro = (lane >> 4) * 4, co = lane & 15;
#pragma unroll
  for (int n = 0; n < 4; n++) {
    const int col = colB + wc + n * 16 + co;
    const float bv = bias[col];
    const int h = col >> 6, d = col & 63;
#pragma unroll
    for (int m = 0; m < 4; m++)
#pragma unroll
      for (int j = 0; j < 4; j++) {
        long r = rowB + wr + m * 16 + ro + j;
        long bq = r >> 10, s = r & 1023;
        Out[(((bq * 16 + h) * 1024 + s) << 6) + d] = f2bf(acc[m][n][j] + bv);
      }
  }
}

// ---- V transpose: (bh, s, d) -> (bh, d, s) ----
__global__ __launch_bounds__(256) void vtrans_kernel(const u16* __restrict__ V,
                                                     u16* __restrict__ Vt) {
  __shared__ u16 t[64][72];
  const int tid = threadIdx.x;
  const int bh = blockIdx.z;
  const int sB = blockIdx.x * 64;
  const u16* src = V + (long)bh * 65536 + (long)sB * 64;
#pragma unroll
  for (int i = 0; i < 4; i++) {
    int idx = i * 256 + tid;
    int r = idx >> 4, c4 = idx & 15;
    ushort4 v = *(const ushort4*)(src + r * 64 + c4 * 4);
    *(ushort4*)&t[r][c4 * 4] = v;
  }
  __syncthreads();
  u16* dst = Vt + (long)bh * 65536 + sB;
#pragma unroll
  for (int i = 0; i < 4; i++) {
    int idx = i * 256 + tid;
    int d = idx >> 4, s4 = idx & 15;
    ushort4 v;
    v.x = t[s4 * 4 + 0][d]; v.y = t[s4 * 4 + 1][d];
    v.z = t[s4 * 4 + 2][d]; v.w = t[s4 * 4 + 3][d];
    *(ushort4*)(dst + (long)d * 1024 + s4 * 4) = v;
  }
}

// ---- fused scores + softmax: attn[q,k] = softmax_k(0.125 * Q.K^T), written once ----
__global__ __launch_bounds__(256) void score_sm_kernel(const u16* __restrict__ Q,
                                                       const u16* __restrict__ K,
                                                       float* __restrict__ attn) {
  __shared__ u16 Qlds[128 * 64];    // 16 KB, resident whole kernel
  __shared__ u16 Klds[128 * 64];    // 16 KB, restaged per k-block (twice)
  __shared__ float redm[2][128];
  __shared__ float redl[2][128];
  const int tid = threadIdx.x, lane = tid & 63, w = tid >> 6;
  const int wr = (w >> 1) * 64, wc = (w & 1) * 64;
  const int z = blockIdx.y;
  const int rowB = blockIdx.x * 128;
  const u16* Qb = Q + (long)z * 65536 + (long)rowB * 64;
  const u16* Kb = K + (long)z * 65536;
  const int ro = (lane >> 4) * 4, co = lane & 15;

  stage_bf16<128, 64>(Qb, 64, Qlds, tid);

  float mrow[16], lrow[16];
#pragma unroll
  for (int i = 0; i < 16; i++) { mrow[i] = -1e30f; lrow[i] = 0.0f; }

  // ---- pass 1: online (max, sumexp) per row ----
  for (int kb = 0; kb < 8; kb++) {
    stage_bf16<128, 64>(Kb + kb * 8192, 64, Klds, tid);
    __syncthreads();
    f32x4 acc[4][4] = {};
    kstep<4, 4, 64>(Qlds, Klds, lane, wr, wc, 0, acc);
    kstep<4, 4, 64>(Qlds, Klds, lane, wr, wc, 32, acc);
    __syncthreads();
#pragma unroll
    for (int m = 0; m < 4; m++)
#pragma unroll
      for (int j = 0; j < 4; j++) {
        const int i = m * 4 + j;
        float s0 = 0.125f * acc[m][0][j], s1 = 0.125f * acc[m][1][j];
        float s2 = 0.125f * acc[m][2][j], s3 = 0.125f * acc[m][3][j];
        float t = fmaxf(fmaxf(s0, s1), fmaxf(s2, s3));
#pragma unroll
        for (int o = 8; o > 0; o >>= 1) t = fmaxf(t, __shfl_xor(t, o, 64));
        const float M = fmaxf(mrow[i], t);
        float e = __expf(s0 - M) + __expf(s1 - M) + __expf(s2 - M) + __expf(s3 - M);
#pragma unroll
        for (int o = 8; o > 0; o >>= 1) e += __shfl_xor(e, o, 64);
        lrow[i] = lrow[i] * __expf(mrow[i] - M) + e;
        mrow[i] = M;
      }
  }

  // ---- cross-wave (col-half) combine ----
  if (co == 0) {
#pragma unroll
    for (int m = 0; m < 4; m++)
#pragma unroll
      for (int j = 0; j < 4; j++) {
        const int r = wr + m * 16 + ro + j;
        redm[w & 1][r] = mrow[m * 4 + j];
        redl[w & 1][r] = lrow[m * 4 + j];
      }
  }
  __syncthreads();
#pragma unroll
  for (int m = 0; m < 4; m++)
#pragma unroll
    for (int j = 0; j < 4; j++) {
      const int i = m * 4 + j;
      const int r = wr + m * 16 + ro + j;
      const float m0 = redm[0][r], m1 = redm[1][r];
      const float l0 = redl[0][r], l1 = redl[1][r];
      const float M = fmaxf(m0, m1);
      const float L = l0 * __expf(m0 - M) + l1 * __expf(m1 - M);
      mrow[i] = M;
      lrow[i] = 1.0f / L;
    }

  // ---- pass 2: recompute scores, write normalized attn exactly once ----
  float* ab = attn + ((long)z << 20) + (long)rowB * 1024;
  for (int kb = 0; kb < 8; kb++) {
    __syncthreads();
    stage_bf16<128, 64>(Kb + kb * 8192, 64, Klds, tid);
    __syncthreads();
    f32x4 acc[4][4] = {};
    kstep<4, 4, 64>(Qlds, Klds, lane, wr, wc, 0, acc);
    kstep<4, 4, 64>(Qlds, Klds, lane, wr, wc, 32, acc);
#pragma unroll
    for (int m = 0; m < 4; m++)
#pragma unroll
      for (int j = 0; j < 4; j++) {
        const int i = m * 4 + j;
        long r = wr + m * 16 + ro + j;
        float* rowp = ab + r * 1024 + kb * 128 + wc;
#pragma unroll
        for (int n = 0; n < 4; n++)
          rowp[n * 16 + co] = __expf(0.125f * acc[m][n][j] - mrow[i]) * lrow[i];
      }
  }
}

// ---- context: C[q,d] = sum_k P[q,k] Vt[d,k]; P fp32 from d_out; out bf16 (B,S,E) ----
__global__ __launch_bounds__(256) void ctx_kernel(const float* __restrict__ attn,
                                                  const u16* __restrict__ Vt,
                                                  u16* __restrict__ Ctx) {
  __shared__ u16 Alds[128 * 64];
  __shared__ u16 Blds[64 * 64];
  const int tid = threadIdx.x, lane = tid & 63, w = tid >> 6;
  const int wr = (w >> 1) * 64, wc = (w & 1) * 32;
  const int z = blockIdx.z, b = z >> 4, h = z & 15;
  const float* Ab = attn + ((long)z << 20);
  const u16* Bb = Vt + (long)z * 65536;
  const long rowB = (long)blockIdx.x * 128;
  f32x4 acc[4][2] = {};
  for (int k0 = 0; k0 < 1024; k0 += 64) {
    stage_f32<128, 64>(Ab + rowB * 1024 + k0, 1024, Alds, tid);
    stage_bf16<64, 64>(Bb + k0, 1024, Blds, tid);
    __syncthreads();
    kstep<4, 2, 64>(Alds, Blds, lane, wr, wc, 0, acc);
    kstep<4, 2, 64>(Alds, Blds, lane, wr, wc, 32, acc);
    __syncthreads();
  }
  const int ro = (lane >> 4) * 4, co = lane & 15;
  u16* cb = Ctx + ((long)b << 20) + h * 64;
#pragma unroll
  for (int m = 0; m < 4; m++)
#pragma unroll
    for (int j = 0; j < 4; j++) {
      long q = rowB + wr + m * 16 + ro + j;
#pragma unroll
      for (int n = 0; n < 2; n++)
        cb[(q << 10) + wc + n * 16 + co] = f2bf(acc[m][n][j]);
    }
}

// ---- out projection (all-bf16): O[s,f] = sum_e Ctx[s,e] W[f,e] + bias[f]; fp32 out ----
__global__ __launch_bounds__(256) void outb_kernel(const u16* __restrict__ Ctx,
                                                   const u16* __restrict__ W,
                                                   const float* __restrict__ bias,
                                                   float* __restrict__ Out) {
  __shared__ u16 Alds[128 * 64];
  __shared__ u16 Blds[128 * 64];
  const int tid = threadIdx.x, lane = tid & 63, w = tid >> 6;
  const int wr = (w >> 1) * 64, wc = (w & 1) * 64;
  const long rowB = (long)blockIdx.y * 128;
  const int colB = blockIdx.x * 128;
  f32x4 acc[4][4] = {};
  for (int k0 = 0; k0 < 1024; k0 += 64) {
    stage_bf16<128, 64>(Ctx + rowB * 1024 + k0, 1024, Alds, tid);
    stage_bf16<128, 64>(W + (long)colB * 1024 + k0, 1024, Blds, tid);
    __syncthreads();
    kstep<4, 4, 64>(Alds, Blds, lane, wr, wc, 0, acc);
    kstep<4, 4, 64>(Alds, Blds, lane, wr, wc, 32, acc);
    __syncthreads();
  }
  const int ro = (lane >> 4) * 4, co = lane & 15;
#pragma unroll
  for (int n = 0; n < 4; n++) {
    const int col = colB + wc + n * 16 + co;
    const float bv = bias[col];
#pragma unroll
    for (int m = 0; m < 4; m++)
#pragma unroll
      for (int j = 0; j < 4; j++) {
        long r = rowB + wr + m * 16 + ro + j;
        Out[r * 1024 + col] = acc[m][n][j] + bv;
      }
  }
}

extern "C" void kernel_launch(void* const* d_in, const int* in_sizes, int n_in,
                              void* d_out, int out_size, void* d_ws, size_t ws_size,
                              hipStream_t stream) {
  const float* query = (const float*)d_in[0];
  const float* key   = (const float*)d_in[1];
  const float* value = (const float*)d_in[2];
  const float* q_w   = (const float*)d_in[3];
  const float* q_b   = (const float*)d_in[4];
  const float* k_w   = (const float*)d_in[5];
  const float* k_b   = (const float*)d_in[6];
  const float* v_w   = (const float*)d_in[7];
  const float* v_b   = (const float*)d_in[8];
  const float* out_w = (const float*)d_in[9];
  const float* out_b = (const float*)d_in[10];

  const long MB = 1048576L;
  char* ws = (char*)d_ws;
  u16* Qp  = (u16*)(ws);             // (B,H,S,D) bf16, 16 MB
  u16* Kp  = (u16*)(ws + 16 * MB);   // 16 MB
  u16* Vp  = (u16*)(ws + 32 * MB);   // 16 MB
  u16* Qb  = (u16*)(ws + 48 * MB);   // bf16 query (dead after projQ)
  u16* Vt  = (u16*)(ws + 48 * MB);   //   ...then Vt (B,H,D,S) aliases it
  u16* Kb  = (u16*)(ws + 64 * MB);   // bf16 key (dead after projK)
  u16* Ctx = (u16*)(ws + 64 * MB);   //   ...then Ctx (B,S,E) aliases it
  u16* Vb  = (u16*)(ws + 80 * MB);   // bf16 value
  u16* Wq  = (u16*)(ws + 96 * MB);   // 2 MB each
  u16* Wk  = (u16*)(ws + 98 * MB);
  u16* Wv  = (u16*)(ws + 100 * MB);
  u16* Wo  = (u16*)(ws + 102 * MB);  // total 104 MB

  float* attn = (float*)d_out;                       // [8,16,1024,1024]
  float* outp = (float*)d_out + 134217728L;          // [8,1024,1024]

  CvtArgs ca;
  ca.s[0] = query; ca.d[0] = Qb; ca.n8[0] = 1048576;
  ca.s[1] = key;   ca.d[1] = Kb; ca.n8[1] = 1048576;
  ca.s[2] = value; ca.d[2] = Vb; ca.n8[2] = 1048576;
  ca.s[3] = q_w;   ca.d[3] = Wq; ca.n8[3] = 131072;
  ca.s[4] = k_w;   ca.d[4] = Wk; ca.n8[4] = 131072;
  ca.s[5] = v_w;   ca.d[5] = Wv; ca.n8[5] = 131072;
  ca.s[6] = out_w; ca.d[6] = Wo; ca.n8[6] = 131072;

  dim3 blk(256);
  cvt_all<<<dim3(2048, 7), blk, 0, stream>>>(ca);
  projb_kernel<<<dim3(8, 64), blk, 0, stream>>>(Qb, Wq, q_b, Qp);
  projb_kernel<<<dim3(8, 64), blk, 0, stream>>>(Kb, Wk, k_b, Kp);
  projb_kernel<<<dim3(8, 64), blk, 0, stream>>>(Vb, Wv, v_b, Vp);
  vtrans_kernel<<<dim3(16, 1, 128), blk, 0, stream>>>(Vp, Vt);
  score_sm_kernel<<<dim3(8, 128), blk, 0, stream>>>(Qp, Kp, attn);
  ctx_kernel<<<dim3(8, 1, 128), blk, 0, stream>>>(attn, Vt, Ctx);
  outb_kernel<<<dim3(8, 64), blk, 0, stream>>>(Ctx, out_w != nullptr ? Wo : Wo, out_b, outp);
}

// Round 4
// 408.558 us; speedup vs baseline: 1.8319x; 1.3602x over previous
//
#include <hip/hip_runtime.h>

typedef __attribute__((ext_vector_type(8))) short short8;   // 8 bf16 in 4 VGPRs
typedef __attribute__((ext_vector_type(4))) float f32x4;
typedef unsigned short u16;

#define DEVI __device__ __forceinline__

DEVI u16 f2bf(float f) {
  unsigned u = __float_as_uint(f);
  unsigned r = (u + 0x7fffu + ((u >> 16) & 1u)) >> 16;   // RNE
  return (u16)r;
}

DEVI void gl2lds16(const void* g, void* l) {
  __builtin_amdgcn_global_load_lds((const __attribute__((address_space(1))) void*)g,
                                   (__attribute__((address_space(3))) void*)l, 16, 0, 0);
}

// stage bf16 tile ROWS x BKE (row-major, ld elems) into linear LDS via global_load_lds
template<int ROWS, int BKE>
DEVI void stage_bf16(const u16* __restrict__ g, int ld, u16* lds, int tid) {
  constexpr int CPR = BKE / 8;          // 16B chunks per row
  constexpr int CH  = ROWS * CPR;
  const int wave = tid >> 6, lane = tid & 63;
#pragma unroll
  for (int i = 0; i < CH / 256; i++) {
    int c = (i * 4 + wave) * 64 + lane;
    int row = c / CPR;
    int colb = (c % CPR) * 16;
    gl2lds16((const char*)g + (long)row * ld * 2 + colb, (char*)lds + (long)c * 16);
  }
}

// one K=32 MFMA step on LDS tiles A[*][BKE], B[*][BKE]; wave tile = (FM*16) x (FN*16)
template<int FM, int FN, int BKE>
DEVI void kstep(const u16* Alds, const u16* Blds, int lane, int wr, int wc, int kk,
                f32x4 (*acc)[FN]) {
  const int ro = lane & 15, ko = kk + (lane >> 4) * 8;
  short8 a[FM], b[FN];
#pragma unroll
  for (int m = 0; m < FM; m++) a[m] = *(const short8*)(Alds + (wr + m * 16 + ro) * BKE + ko);
#pragma unroll
  for (int n = 0; n < FN; n++) b[n] = *(const short8*)(Blds + (wc + n * 16 + ro) * BKE + ko);
#pragma unroll
  for (int m = 0; m < FM; m++)
#pragma unroll
    for (int n = 0; n < FN; n++)
      acc[m][n] = __builtin_amdgcn_mfma_f32_16x16x32_bf16(a[m], b[n], acc[m][n], 0, 0, 0);
}

// ---- fp32 -> bf16 conversion for up to 7 tensors ----
struct CvtArgs {
  const float* s[7];
  u16* d[7];
  int n8[7];
};

__global__ __launch_bounds__(256) void cvt_all(CvtArgs a) {
  const int t = blockIdx.y;
  const int n = a.n8[t];
  const float* __restrict__ s = a.s[t];
  u16* __restrict__ d = a.d[t];
  for (long i = blockIdx.x * 256 + threadIdx.x; i < n; i += (long)gridDim.x * 256) {
    float4 v0 = ((const float4*)s)[2 * i];
    float4 v1 = ((const float4*)s)[2 * i + 1];
    ushort4 h0, h1;
    h0.x = f2bf(v0.x); h0.y = f2bf(v0.y); h0.z = f2bf(v0.z); h0.w = f2bf(v0.w);
    h1.x = f2bf(v1.x); h1.y = f2bf(v1.y); h1.z = f2bf(v1.z); h1.w = f2bf(v1.w);
    ((ushort4*)d)[2 * i] = h0;
    ((ushort4*)d)[2 * i + 1] = h1;
  }
}

// ---- projection (all-bf16): Y[s,f] = sum_e X[s,e] W[f,e] + bias[f]; out bf16 (B,H,S,D) ----
__global__ __launch_bounds__(256) void projb_kernel(const u16* __restrict__ X,
                                                    const u16* __restrict__ W,
                                                    const float* __restrict__ bias,
                                                    u16* __restrict__ Out) {
  __shared__ u16 Alds[128 * 64];
  __shared__ u16 Blds[128 * 64];
  const int tid = threadIdx.x, lane = tid & 63, w = tid >> 6;
  const int wr = (w >> 1) * 64, wc = (w & 1) * 64;
  const long rowB = (long)blockIdx.y * 128;
  const int colB = blockIdx.x * 128;
  f32x4 acc[4][4] = {};
  for (int k0 = 0; k0 < 1024; k0 += 64) {
    stage_bf16<128, 64>(X + rowB * 1024 + k0, 1024, Alds, tid);
    stage_bf16<128, 64>(W + (long)colB * 1024 + k0, 1024, Blds, tid);
    __syncthreads();
    kstep<4, 4, 64>(Alds, Blds, lane, wr, wc, 0, acc);
    kstep<4, 4, 64>(Alds, Blds, lane, wr, wc, 32, acc);
    __syncthreads();
  }
  const int ro = (lane >> 4) * 4, co = lane & 15;
#pragma unroll
  for (int n = 0; n < 4; n++) {
    const int col = colB + wc + n * 16 + co;
    const float bv = bias[col];
    const int h = col >> 6, d = col & 63;
#pragma unroll
    for (int m = 0; m < 4; m++)
#pragma unroll
      for (int j = 0; j < 4; j++) {
        long r = rowB + wr + m * 16 + ro + j;
        long bq = r >> 10, s = r & 1023;
        Out[(((bq * 16 + h) * 1024 + s) << 6) + d] = f2bf(acc[m][n][j] + bv);
      }
  }
}

// ---- V transpose: (bh, s, d) -> (bh, d, s) ----
__global__ __launch_bounds__(256) void vtrans_kernel(const u16* __restrict__ V,
                                                     u16* __restrict__ Vt) {
  __shared__ u16 t[64][72];
  const int tid = threadIdx.x;
  const int bh = blockIdx.z;
  const int sB = blockIdx.x * 64;
  const u16* src = V + (long)bh * 65536 + (long)sB * 64;
#pragma unroll
  for (int i = 0; i < 4; i++) {
    int idx = i * 256 + tid;
    int r = idx >> 4, c4 = idx & 15;
    ushort4 v = *(const ushort4*)(src + r * 64 + c4 * 4);
    *(ushort4*)&t[r][c4 * 4] = v;
  }
  __syncthreads();
  u16* dst = Vt + (long)bh * 65536 + sB;
#pragma unroll
  for (int i = 0; i < 4; i++) {
    int idx = i * 256 + tid;
    int d = idx >> 4, s4 = idx & 15;
    ushort4 v;
    v.x = t[s4 * 4 + 0][d]; v.y = t[s4 * 4 + 1][d];
    v.z = t[s4 * 4 + 2][d]; v.w = t[s4 * 4 + 3][d];
    *(ushort4*)(dst + (long)d * 1024 + s4 * 4) = v;
  }
}

// ---- fused flash: attn = softmax(0.125*QK^T) written once (never re-read),
//      Ctx = attn @ V accumulated in-kernel. Wave owns 32 q-rows, full k width.
//      Conservative barriers (no staging/compute overlap): race-screened structure. ----
__global__ __launch_bounds__(256) void flash_kernel(const u16* __restrict__ Q,
                                                    const u16* __restrict__ K,
                                                    const u16* __restrict__ Vt,
                                                    float* __restrict__ attn,
                                                    u16* __restrict__ Ctx) {
  __shared__ u16 Klds[64 * 64];    // [k=64][d=64]   8 KB
  __shared__ u16 Vlds[64 * 64];    // [d=64][k=64]   8 KB
  __shared__ u16 Plds[128 * 64];   // [q=128][k=64] 16 KB, XOR-swizzled, wave-private rows
  const int tid = threadIdx.x, lane = tid & 63, w = tid >> 6;
  const int z = blockIdx.x;                 // b*16+h
  const int rowB = blockIdx.y * 128;
  const int b = z >> 4, h = z & 15;
  const u16* Qb  = Q  + (long)z * 65536 + (long)rowB * 64;
  const u16* Kb  = K  + (long)z * 65536;
  const u16* Vtb = Vt + (long)z * 65536;
  const int ro = lane & 15, ko8 = (lane >> 4) * 8;
  const int qw = w * 32;                    // wave's q offset in tile

  // Q fragments resident in registers for the whole kernel
  short8 aq[2][2];
#pragma unroll
  for (int m = 0; m < 2; m++)
#pragma unroll
    for (int kt = 0; kt < 2; kt++)
      aq[m][kt] = *(const short8*)(Qb + (qw + m * 16 + ro) * 64 + kt * 32 + ko8);

  float mrow[8], lrow[8];
#pragma unroll
  for (int i = 0; i < 8; i++) { mrow[i] = -1e30f; lrow[i] = 0.0f; }

  // ---- pass 1: online (max, sumexp); stats wave-local. stage -> sync -> compute -> sync ----
  for (int kb = 0; kb < 16; kb++) {
    stage_bf16<64, 64>(Kb + kb * 4096, 64, Klds, tid);
    __syncthreads();                         // staging drained, visible to all
    f32x4 acc[2][4] = {};
#pragma unroll
    for (int kt = 0; kt < 2; kt++) {
      short8 bfr[4];
#pragma unroll
      for (int n = 0; n < 4; n++)
        bfr[n] = *(const short8*)(Klds + (n * 16 + ro) * 64 + kt * 32 + ko8);
#pragma unroll
      for (int m = 0; m < 2; m++)
#pragma unroll
        for (int n = 0; n < 4; n++)
          acc[m][n] = __builtin_amdgcn_mfma_f32_16x16x32_bf16(aq[m][kt], bfr[n], acc[m][n], 0, 0, 0);
    }
    __syncthreads();                         // all Klds reads done before restage
#pragma unroll
    for (int m = 0; m < 2; m++)
#pragma unroll
      for (int j = 0; j < 4; j++) {
        const int i = m * 4 + j;
        float s0 = 0.125f * acc[m][0][j], s1 = 0.125f * acc[m][1][j];
        float s2 = 0.125f * acc[m][2][j], s3 = 0.125f * acc[m][3][j];
        float t = fmaxf(fmaxf(s0, s1), fmaxf(s2, s3));
#pragma unroll
        for (int o = 8; o > 0; o >>= 1) t = fmaxf(t, __shfl_xor(t, o, 64));
        const float M = fmaxf(mrow[i], t);
        float e = __expf(s0 - M) + __expf(s1 - M) + __expf(s2 - M) + __expf(s3 - M);
#pragma unroll
        for (int o = 8; o > 0; o >>= 1) e += __shfl_xor(e, o, 64);
        lrow[i] = lrow[i] * __expf(mrow[i] - M) + e;
        mrow[i] = M;
      }
  }
#pragma unroll
  for (int i = 0; i < 8; i++) lrow[i] = 1.0f / lrow[i];

  // ---- pass 2: recompute S, write attn once, accumulate O = P @ V^T ----
  f32x4 acc_o[2][4] = {};
  float* ab = attn + ((long)z << 20) + (long)rowB * 1024;
  for (int kb = 0; kb < 16; kb++) {
    stage_bf16<64, 64>(Kb + kb * 4096, 64, Klds, tid);
    stage_bf16<64, 64>(Vtb + kb * 64, 1024, Vlds, tid);
    __syncthreads();                         // staging drained
    f32x4 acc[2][4] = {};
#pragma unroll
    for (int kt = 0; kt < 2; kt++) {
      short8 bfr[4];
#pragma unroll
      for (int n = 0; n < 4; n++)
        bfr[n] = *(const short8*)(Klds + (n * 16 + ro) * 64 + kt * 32 + ko8);
#pragma unroll
      for (int m = 0; m < 2; m++)
#pragma unroll
        for (int n = 0; n < 4; n++)
          acc[m][n] = __builtin_amdgcn_mfma_f32_16x16x32_bf16(aq[m][kt], bfr[n], acc[m][n], 0, 0, 0);
    }
    // normalized P: write attn (streaming) + wave-private swizzled Plds
#pragma unroll
    for (int m = 0; m < 2; m++)
#pragma unroll
      for (int j = 0; j < 4; j++) {
        const int i = m * 4 + j;
        const int ql = qw + m * 16 + (lane >> 4) * 4 + j;   // local q row
        float* rowp = ab + (long)ql * 1024 + kb * 64;
        u16* prow = Plds + ql * 64;
        const int sw = ((ql & 7) << 3);
#pragma unroll
        for (int n = 0; n < 4; n++) {
          const int col = n * 16 + (lane & 15);
          float p = __expf(0.125f * acc[m][n][j] - mrow[i]) * lrow[i];
          __builtin_nontemporal_store(p, rowp + col);
          prow[col ^ sw] = f2bf(p);
        }
      }
    __syncthreads();                         // P writes complete before PV reads
    // PV: acc_o += P(own rows, Plds) * V(Vlds)
#pragma unroll
    for (int kt = 0; kt < 2; kt++) {
      short8 pa[2], bv[4];
#pragma unroll
      for (int m = 0; m < 2; m++) {
        const int row = qw + m * 16 + ro;
        pa[m] = *(const short8*)(Plds + row * 64 + ((kt * 32 + ko8) ^ ((row & 7) << 3)));
      }
#pragma unroll
      for (int n = 0; n < 4; n++)
        bv[n] = *(const short8*)(Vlds + (n * 16 + ro) * 64 + kt * 32 + ko8);
#pragma unroll
      for (int m = 0; m < 2; m++)
#pragma unroll
        for (int n = 0; n < 4; n++)
          acc_o[m][n] = __builtin_amdgcn_mfma_f32_16x16x32_bf16(pa[m], bv[n], acc_o[m][n], 0, 0, 0);
    }
    __syncthreads();                         // all LDS reads done before next stage
  }

  // write Ctx (B,S,E) bf16
  u16* cb = Ctx + ((long)b << 20) + (long)h * 64;
#pragma unroll
  for (int m = 0; m < 2; m++)
#pragma unroll
    for (int j = 0; j < 4; j++) {
      const long s = rowB + qw + m * 16 + (lane >> 4) * 4 + j;
#pragma unroll
      for (int n = 0; n < 4; n++)
        cb[s * 1024 + n * 16 + (lane & 15)] = f2bf(acc_o[m][n][j]);
    }
}

// ---- out projection (all-bf16): O[s,f] = sum_e Ctx[s,e] W[f,e] + bias[f]; fp32 out ----
__global__ __launch_bounds__(256) void outb_kernel(const u16* __restrict__ Ctx,
                                                   const u16* __restrict__ W,
                                                   const float* __restrict__ bias,
                                                   float* __restrict__ Out) {
  __shared__ u16 Alds[128 * 64];
  __shared__ u16 Blds[128 * 64];
  const int tid = threadIdx.x, lane = tid & 63, w = tid >> 6;
  const int wr = (w >> 1) * 64, wc = (w & 1) * 64;
  const long rowB = (long)blockIdx.y * 128;
  const int colB = blockIdx.x * 128;
  f32x4 acc[4][4] = {};
  for (int k0 = 0; k0 < 1024; k0 += 64) {
    stage_bf16<128, 64>(Ctx + rowB * 1024 + k0, 1024, Alds, tid);
    stage_bf16<128, 64>(W + (long)colB * 1024 + k0, 1024, Blds, tid);
    __syncthreads();
    kstep<4, 4, 64>(Alds, Blds, lane, wr, wc, 0, acc);
    kstep<4, 4, 64>(Alds, Blds, lane, wr, wc, 32, acc);
    __syncthreads();
  }
  const int ro = (lane >> 4) * 4, co = lane & 15;
#pragma unroll
  for (int n = 0; n < 4; n++) {
    const int col = colB + wc + n * 16 + co;
    const float bv = bias[col];
#pragma unroll
    for (int m = 0; m < 4; m++)
#pragma unroll
      for (int j = 0; j < 4; j++) {
        long r = rowB + wr + m * 16 + ro + j;
        __builtin_nontemporal_store(acc[m][n][j] + bv, Out + r * 1024 + col);
      }
  }
}

extern "C" void kernel_launch(void* const* d_in, const int* in_sizes, int n_in,
                              void* d_out, int out_size, void* d_ws, size_t ws_size,
                              hipStream_t stream) {
  const float* query = (const float*)d_in[0];
  const float* key   = (const float*)d_in[1];
  const float* value = (const float*)d_in[2];
  const float* q_w   = (const float*)d_in[3];
  const float* q_b   = (const float*)d_in[4];
  const float* k_w   = (const float*)d_in[5];
  const float* k_b   = (const float*)d_in[6];
  const float* v_w   = (const float*)d_in[7];
  const float* v_b   = (const float*)d_in[8];
  const float* out_w = (const float*)d_in[9];
  const float* out_b = (const float*)d_in[10];

  const long MB = 1048576L;
  char* ws = (char*)d_ws;
  u16* Qp  = (u16*)(ws);             // (B,H,S,D) bf16, 16 MB
  u16* Kp  = (u16*)(ws + 16 * MB);   // 16 MB
  u16* Vp  = (u16*)(ws + 32 * MB);   // 16 MB
  u16* Qb  = (u16*)(ws + 48 * MB);   // bf16 query (dead after projQ)
  u16* Vt  = (u16*)(ws + 48 * MB);   //   ...then Vt (B,H,D,S) aliases it
  u16* Kb  = (u16*)(ws + 64 * MB);   // bf16 key (dead after projK)
  u16* Ctx = (u16*)(ws + 64 * MB);   //   ...then Ctx (B,S,E) aliases it
  u16* Vb  = (u16*)(ws + 80 * MB);   // bf16 value
  u16* Wq  = (u16*)(ws + 96 * MB);   // 2 MB each
  u16* Wk  = (u16*)(ws + 98 * MB);
  u16* Wv  = (u16*)(ws + 100 * MB);
  u16* Wo  = (u16*)(ws + 102 * MB);  // total 104 MB

  float* attn = (float*)d_out;                       // [8,16,1024,1024]
  float* outp = (float*)d_out + 134217728L;          // [8,1024,1024]

  CvtArgs ca;
  ca.s[0] = query; ca.d[0] = Qb; ca.n8[0] = 1048576;
  ca.s[1] = key;   ca.d[1] = Kb; ca.n8[1] = 1048576;
  ca.s[2] = value; ca.d[2] = Vb; ca.n8[2] = 1048576;
  ca.s[3] = q_w;   ca.d[3] = Wq; ca.n8[3] = 131072;
  ca.s[4] = k_w;   ca.d[4] = Wk; ca.n8[4] = 131072;
  ca.s[5] = v_w;   ca.d[5] = Wv; ca.n8[5] = 131072;
  ca.s[6] = out_w; ca.d[6] = Wo; ca.n8[6] = 131072;

  dim3 blk(256);
  cvt_all<<<dim3(2048, 7), blk, 0, stream>>>(ca);
  projb_kernel<<<dim3(8, 64), blk, 0, stream>>>(Qb, Wq, q_b, Qp);
  projb_kernel<<<dim3(8, 64), blk, 0, stream>>>(Kb, Wk, k_b, Kp);
  projb_kernel<<<dim3(8, 64), blk, 0, stream>>>(Vb, Wv, v_b, Vp);
  vtrans_kernel<<<dim3(16, 1, 128), blk, 0, stream>>>(Vp, Vt);
  flash_kernel<<<dim3(128, 8), blk, 0, stream>>>(Qp, Kp, Vt, attn, Ctx);
  outb_kernel<<<dim3(8, 64), blk, 0, stream>>>(Ctx, Wo, out_b, outp);
}

// Round 5
// 359.968 us; speedup vs baseline: 2.0792x; 1.1350x over previous
//
#include <hip/hip_runtime.h>

typedef __attribute__((ext_vector_type(8))) short short8;   // 8 bf16 in 4 VGPRs
typedef __attribute__((ext_vector_type(4))) float f32x4;
typedef unsigned short u16;

#define DEVI __device__ __forceinline__

DEVI u16 f2bf(float f) {
  unsigned u = __float_as_uint(f);
  unsigned r = (u + 0x7fffu + ((u >> 16) & 1u)) >> 16;   // RNE
  return (u16)r;
}

DEVI void gl2lds16(const void* g, void* l) {
  __builtin_amdgcn_global_load_lds((const __attribute__((address_space(1))) void*)g,
                                   (__attribute__((address_space(3))) void*)l, 16, 0, 0);
}

// stage bf16 tile ROWS x BKE (row-major, ld elems) into linear LDS via global_load_lds
template<int ROWS, int BKE>
DEVI void stage_bf16(const u16* __restrict__ g, int ld, u16* lds, int tid) {
  constexpr int CPR = BKE / 8;          // 16B chunks per row
  constexpr int CH  = ROWS * CPR;
  const int wave = tid >> 6, lane = tid & 63;
#pragma unroll
  for (int i = 0; i < CH / 256; i++) {
    int c = (i * 4 + wave) * 64 + lane;
    int row = c / CPR;
    int colb = (c % CPR) * 16;
    gl2lds16((const char*)g + (long)row * ld * 2 + colb, (char*)lds + (long)c * 16);
  }
}

// one K=32 MFMA step on LDS tiles A[*][BKE], B[*][BKE]; wave tile = (FM*16) x (FN*16)
template<int FM, int FN, int BKE>
DEVI void kstep(const u16* Alds, const u16* Blds, int lane, int wr, int wc, int kk,
                f32x4 (*acc)[FN]) {
  const int ro = lane & 15, ko = kk + (lane >> 4) * 8;
  short8 a[FM], b[FN];
#pragma unroll
  for (int m = 0; m < FM; m++) a[m] = *(const short8*)(Alds + (wr + m * 16 + ro) * BKE + ko);
#pragma unroll
  for (int n = 0; n < FN; n++) b[n] = *(const short8*)(Blds + (wc + n * 16 + ro) * BKE + ko);
#pragma unroll
  for (int m = 0; m < FM; m++)
#pragma unroll
    for (int n = 0; n < FN; n++)
      acc[m][n] = __builtin_amdgcn_mfma_f32_16x16x32_bf16(a[m], b[n], acc[m][n], 0, 0, 0);
}

// ---- fp32 -> bf16 conversion for up to 7 tensors ----
struct CvtArgs {
  const float* s[7];
  u16* d[7];
  int n8[7];
};

__global__ __launch_bounds__(256) void cvt_all(CvtArgs a) {
  const int t = blockIdx.y;
  const int n = a.n8[t];
  const float* __restrict__ s = a.s[t];
  u16* __restrict__ d = a.d[t];
  for (long i = blockIdx.x * 256 + threadIdx.x; i < n; i += (long)gridDim.x * 256) {
    float4 v0 = ((const float4*)s)[2 * i];
    float4 v1 = ((const float4*)s)[2 * i + 1];
    ushort4 h0, h1;
    h0.x = f2bf(v0.x); h0.y = f2bf(v0.y); h0.z = f2bf(v0.z); h0.w = f2bf(v0.w);
    h1.x = f2bf(v1.x); h1.y = f2bf(v1.y); h1.z = f2bf(v1.z); h1.w = f2bf(v1.w);
    ((ushort4*)d)[2 * i] = h0;
    ((ushort4*)d)[2 * i + 1] = h1;
  }
}

// ---- merged QKV projection (all-bf16): Y[s,f] = sum_e X[s,e] W[f,e] + bias[f]
//      z=0: Q, scaled by 0.125, out (B,H,S,D). z=1: K, out (B,H,S,D).
//      z=2: V, out TRANSPOSED (B,H,D,S) -- replaces vtrans kernel. ----
struct Biases { const float* p[3]; };

__global__ __launch_bounds__(256) void proj3_kernel(const u16* __restrict__ Xb,
                                                    const u16* __restrict__ Wb,
                                                    Biases bs,
                                                    u16* __restrict__ Outb) {
  __shared__ u16 Alds[128 * 64];
  __shared__ u16 Blds[128 * 64];
  const int tid = threadIdx.x, lane = tid & 63, w = tid >> 6;
  const int wr = (w >> 1) * 64, wc = (w & 1) * 64;
  const int z = blockIdx.z;
  const u16* X = Xb + (long)z * 8388608;
  const u16* W = Wb + (long)z * 1048576;
  const float* bias = bs.p[z];
  u16* Out = Outb + (long)z * 8388608;
  const long rowB = (long)blockIdx.y * 128;
  const int colB = blockIdx.x * 128;
  f32x4 acc[4][4] = {};
  for (int k0 = 0; k0 < 1024; k0 += 64) {
    stage_bf16<128, 64>(X + rowB * 1024 + k0, 1024, Alds, tid);
    stage_bf16<128, 64>(W + (long)colB * 1024 + k0, 1024, Blds, tid);
    __syncthreads();
    kstep<4, 4, 64>(Alds, Blds, lane, wr, wc, 0, acc);
    kstep<4, 4, 64>(Alds, Blds, lane, wr, wc, 32, acc);
    __syncthreads();
  }
  const int ro = (lane >> 4) * 4, co = lane & 15;
  const float sc = (z == 0) ? 0.125f : 1.0f;
  if (z < 2) {
#pragma unroll
    for (int n = 0; n < 4; n++) {
      const int col = colB + wc + n * 16 + co;
      const float bv = bias[col];
      const int h = col >> 6, d = col & 63;
#pragma unroll
      for (int m = 0; m < 4; m++)
#pragma unroll
        for (int j = 0; j < 4; j++) {
          long r = rowB + wr + m * 16 + ro + j;
          long bq = r >> 10, s = r & 1023;
          Out[(((bq * 16 + h) * 1024 + s) << 6) + d] = f2bf((acc[m][n][j] + bv) * sc);
        }
    }
  } else {
    // transposed: Vt[bh][d][s], s contiguous over j -> ushort4 store
#pragma unroll
    for (int n = 0; n < 4; n++) {
      const int col = colB + wc + n * 16 + co;
      const float bv = bias[col];
      const long h = col >> 6, d = col & 63;
#pragma unroll
      for (int m = 0; m < 4; m++) {
        long r0 = rowB + wr + m * 16 + ro;
        long bq = r0 >> 10, s = r0 & 1023;
        ushort4 pk;
        pk.x = f2bf(acc[m][n][0] + bv);
        pk.y = f2bf(acc[m][n][1] + bv);
        pk.z = f2bf(acc[m][n][2] + bv);
        pk.w = f2bf(acc[m][n][3] + bv);
        *(ushort4*)(Out + (((bq * 16 + h) << 16) | (d << 10) | s)) = pk;
      }
    }
  }
}

// ---- fused flash: attn = softmax(Q.K^T) written once (never re-read; scale folded
//      into Q), Ctx = attn @ V accumulated in-kernel. Wave owns 32 q-rows.
//      2-phase double-buffered K/V staging (T3-minimum template): prefetch(buf^1)
//      -> compute(buf[cur]) -> one barrier. P RAW within wave: lgkmcnt(0) only. ----
__global__ __launch_bounds__(256) void flash_kernel(const u16* __restrict__ Q,
                                                    const u16* __restrict__ K,
                                                    const u16* __restrict__ Vt,
                                                    float* __restrict__ attn,
                                                    u16* __restrict__ Ctx) {
  __shared__ u16 Klds[2 * 64 * 64];  // dbuf [k=64][d=64]  16 KB
  __shared__ u16 Vlds[2 * 64 * 64];  // dbuf [d=64][k=64]  16 KB
  __shared__ u16 Plds[128 * 64];     // [q=128][k=64] 16 KB, XOR-swizzled, wave-private rows
  const int tid = threadIdx.x, lane = tid & 63, w = tid >> 6;
  const int z = blockIdx.x;                 // b*16+h; all 8 rowB-blocks of z -> same XCD
  const int rowB = blockIdx.y * 128;
  const int b = z >> 4, h = z & 15;
  const u16* Qb  = Q  + (long)z * 65536 + (long)rowB * 64;
  const u16* Kb  = K  + (long)z * 65536;
  const u16* Vtb = Vt + (long)z * 65536;
  const int ro = lane & 15, ko8 = (lane >> 4) * 8;
  const int qw = w * 32;                    // wave's q offset in tile

  // Q fragments resident in registers for the whole kernel (Q pre-scaled by 0.125)
  short8 aq[2][2];
#pragma unroll
  for (int m = 0; m < 2; m++)
#pragma unroll
    for (int kt = 0; kt < 2; kt++)
      aq[m][kt] = *(const short8*)(Qb + (qw + m * 16 + ro) * 64 + kt * 32 + ko8);

  float mrow[8], lrow[8];
#pragma unroll
  for (int i = 0; i < 8; i++) { mrow[i] = -1e30f; lrow[i] = 0.0f; }

  // ---- pass 1: online (max, sumexp); stats wave-local; K double-buffered ----
  stage_bf16<64, 64>(Kb, 64, Klds, tid);
  __syncthreads();
  for (int kb = 0; kb < 16; kb++) {
    const int cur = kb & 1, nxt = cur ^ 1;
    if (kb < 15) stage_bf16<64, 64>(Kb + (kb + 1) * 4096, 64, Klds + nxt * 4096, tid);
    const u16* Kc = Klds + cur * 4096;
    f32x4 acc[2][4] = {};
#pragma unroll
    for (int kt = 0; kt < 2; kt++) {
      short8 bfr[4];
#pragma unroll
      for (int n = 0; n < 4; n++)
        bfr[n] = *(const short8*)(Kc + (n * 16 + ro) * 64 + kt * 32 + ko8);
#pragma unroll
      for (int m = 0; m < 2; m++)
#pragma unroll
        for (int n = 0; n < 4; n++)
          acc[m][n] = __builtin_amdgcn_mfma_f32_16x16x32_bf16(aq[m][kt], bfr[n], acc[m][n], 0, 0, 0);
    }
#pragma unroll
    for (int m = 0; m < 2; m++)
#pragma unroll
      for (int j = 0; j < 4; j++) {
        const int i = m * 4 + j;
        float s0 = acc[m][0][j], s1 = acc[m][1][j];
        float s2 = acc[m][2][j], s3 = acc[m][3][j];
        float t = fmaxf(fmaxf(s0, s1), fmaxf(s2, s3));
#pragma unroll
        for (int o = 8; o > 0; o >>= 1) t = fmaxf(t, __shfl_xor(t, o, 64));
        const float M = fmaxf(mrow[i], t);
        float e = __expf(s0 - M) + __expf(s1 - M) + __expf(s2 - M) + __expf(s3 - M);
#pragma unroll
        for (int o = 8; o > 0; o >>= 1) e += __shfl_xor(e, o, 64);
        lrow[i] = lrow[i] * __expf(mrow[i] - M) + e;
        mrow[i] = M;
      }
    __syncthreads();   // drains prefetch (vmcnt0) + all reads of Kc done before overwrite
  }
#pragma unroll
  for (int i = 0; i < 8; i++) lrow[i] = 1.0f / lrow[i];

  // ---- pass 2: recompute S, write attn once, accumulate O = P @ V^T; K,V dbuf ----
  f32x4 acc_o[2][4] = {};
  float* ab = attn + ((long)z << 20) + (long)rowB * 1024;
  stage_bf16<64, 64>(Kb, 64, Klds, tid);
  stage_bf16<64, 64>(Vtb, 1024, Vlds, tid);
  __syncthreads();
  for (int kb = 0; kb < 16; kb++) {
    const int cur = kb & 1, nxt = cur ^ 1;
    if (kb < 15) {
      stage_bf16<64, 64>(Kb + (kb + 1) * 4096, 64, Klds + nxt * 4096, tid);
      stage_bf16<64, 64>(Vtb + (kb + 1) * 64, 1024, Vlds + nxt * 4096, tid);
    }
    const u16* Kc = Klds + cur * 4096;
    const u16* Vc = Vlds + cur * 4096;
    f32x4 acc[2][4] = {};
#pragma unroll
    for (int kt = 0; kt < 2; kt++) {
      short8 bfr[4];
#pragma unroll
      for (int n = 0; n < 4; n++)
        bfr[n] = *(const short8*)(Kc + (n * 16 + ro) * 64 + kt * 32 + ko8);
#pragma unroll
      for (int m = 0; m < 2; m++)
#pragma unroll
        for (int n = 0; n < 4; n++)
          acc[m][n] = __builtin_amdgcn_mfma_f32_16x16x32_bf16(aq[m][kt], bfr[n], acc[m][n], 0, 0, 0);
    }
    // normalized P: write attn (streaming) + wave-private swizzled Plds
#pragma unroll
    for (int m = 0; m < 2; m++)
#pragma unroll
      for (int j = 0; j < 4; j++) {
        const int i = m * 4 + j;
        const int ql = qw + m * 16 + (lane >> 4) * 4 + j;   // local q row
        float* rowp = ab + (long)ql * 1024 + kb * 64;
        u16* prow = Plds + ql * 64;
        const int sw = ((ql & 7) << 3);
#pragma unroll
        for (int n = 0; n < 4; n++) {
          const int col = n * 16 + (lane & 15);
          float p = __expf(acc[m][n][j] - mrow[i]) * lrow[i];
          __builtin_nontemporal_store(p, rowp + col);
          prow[col ^ sw] = f2bf(p);
        }
      }
    // own-wave P writes visible (cross-lane within wave); does NOT drain vmcnt prefetch
    asm volatile("s_waitcnt lgkmcnt(0)" ::: "memory");
    __builtin_amdgcn_sched_barrier(0);
    // PV: acc_o += P(own rows, Plds) * V(Vc)
#pragma unroll
    for (int kt = 0; kt < 2; kt++) {
      short8 pa[2], bv[4];
#pragma unroll
      for (int m = 0; m < 2; m++) {
        const int row = qw + m * 16 + ro;
        pa[m] = *(const short8*)(Plds + row * 64 + ((kt * 32 + ko8) ^ ((row & 7) << 3)));
      }
#pragma unroll
      for (int n = 0; n < 4; n++)
        bv[n] = *(const short8*)(Vc + (n * 16 + ro) * 64 + kt * 32 + ko8);
#pragma unroll
      for (int m = 0; m < 2; m++)
#pragma unroll
        for (int n = 0; n < 4; n++)
          acc_o[m][n] = __builtin_amdgcn_mfma_f32_16x16x32_bf16(pa[m], bv[n], acc_o[m][n], 0, 0, 0);
    }
    __syncthreads();   // drains prefetch + all LDS reads done before buffer reuse
  }

  // write Ctx (B,S,E) bf16
  u16* cb = Ctx + ((long)b << 20) + (long)h * 64;
#pragma unroll
  for (int m = 0; m < 2; m++)
#pragma unroll
    for (int j = 0; j < 4; j++) {
      const long s = rowB + qw + m * 16 + (lane >> 4) * 4 + j;
#pragma unroll
      for (int n = 0; n < 4; n++)
        cb[s * 1024 + n * 16 + (lane & 15)] = f2bf(acc_o[m][n][j]);
    }
}

// ---- out projection (all-bf16): O[s,f] = sum_e Ctx[s,e] W[f,e] + bias[f]; fp32 out ----
__global__ __launch_bounds__(256) void outb_kernel(const u16* __restrict__ Ctx,
                                                   const u16* __restrict__ W,
                                                   const float* __restrict__ bias,
                                                   float* __restrict__ Out) {
  __shared__ u16 Alds[128 * 64];
  __shared__ u16 Blds[128 * 64];
  const int tid = threadIdx.x, lane = tid & 63, w = tid >> 6;
  const int wr = (w >> 1) * 64, wc = (w & 1) * 64;
  const long rowB = (long)blockIdx.y * 128;
  const int colB = blockIdx.x * 128;
  f32x4 acc[4][4] = {};
  for (int k0 = 0; k0 < 1024; k0 += 64) {
    stage_bf16<128, 64>(Ctx + rowB * 1024 + k0, 1024, Alds, tid);
    stage_bf16<128, 64>(W + (long)colB * 1024 + k0, 1024, Blds, tid);
    __syncthreads();
    kstep<4, 4, 64>(Alds, Blds, lane, wr, wc, 0, acc);
    kstep<4, 4, 64>(Alds, Blds, lane, wr, wc, 32, acc);
    __syncthreads();
  }
  const int ro = (lane >> 4) * 4, co = lane & 15;
#pragma unroll
  for (int n = 0; n < 4; n++) {
    const int col = colB + wc + n * 16 + co;
    const float bv = bias[col];
#pragma unroll
    for (int m = 0; m < 4; m++)
#pragma unroll
      for (int j = 0; j < 4; j++) {
        long r = rowB + wr + m * 16 + ro + j;
        __builtin_nontemporal_store(acc[m][n][j] + bv, Out + r * 1024 + col);
      }
  }
}

extern "C" void kernel_launch(void* const* d_in, const int* in_sizes, int n_in,
                              void* d_out, int out_size, void* d_ws, size_t ws_size,
                              hipStream_t stream) {
  const float* query = (const float*)d_in[0];
  const float* key   = (const float*)d_in[1];
  const float* value = (const float*)d_in[2];
  const float* q_w   = (const float*)d_in[3];
  const float* q_b   = (const float*)d_in[4];
  const float* k_w   = (const float*)d_in[5];
  const float* k_b   = (const float*)d_in[6];
  const float* v_w   = (const float*)d_in[7];
  const float* v_b   = (const float*)d_in[8];
  const float* out_w = (const float*)d_in[9];
  const float* out_b = (const float*)d_in[10];

  const long MB = 1048576L;
  char* ws = (char*)d_ws;
  u16* Qp  = (u16*)(ws);             // (B,H,S,D) bf16 (0.125-scaled), 16 MB
  u16* Kp  = (u16*)(ws + 16 * MB);   // (B,H,S,D) 16 MB
  u16* Vt  = (u16*)(ws + 32 * MB);   // (B,H,D,S) 16 MB (written directly by proj z=2)
  u16* Qb  = (u16*)(ws + 48 * MB);   // bf16 query input   } consecutive, stride 16 MB
  u16* Kb  = (u16*)(ws + 64 * MB);   // bf16 key input     }
  u16* Vb  = (u16*)(ws + 80 * MB);   // bf16 value input   }
  u16* Ctx = (u16*)(ws + 64 * MB);   // (B,S,E) aliases Kb (dead after proj3)
  u16* Wq  = (u16*)(ws + 96 * MB);   // 2 MB each, consecutive
  u16* Wk  = (u16*)(ws + 98 * MB);
  u16* Wv  = (u16*)(ws + 100 * MB);
  u16* Wo  = (u16*)(ws + 102 * MB);  // total 104 MB

  float* attn = (float*)d_out;                       // [8,16,1024,1024]
  float* outp = (float*)d_out + 134217728L;          // [8,1024,1024]

  CvtArgs ca;
  ca.s[0] = query; ca.d[0] = Qb; ca.n8[0] = 1048576;
  ca.s[1] = key;   ca.d[1] = Kb; ca.n8[1] = 1048576;
  ca.s[2] = value; ca.d[2] = Vb; ca.n8[2] = 1048576;
  ca.s[3] = q_w;   ca.d[3] = Wq; ca.n8[3] = 131072;
  ca.s[4] = k_w;   ca.d[4] = Wk; ca.n8[4] = 131072;
  ca.s[5] = v_w;   ca.d[5] = Wv; ca.n8[5] = 131072;
  ca.s[6] = out_w; ca.d[6] = Wo; ca.n8[6] = 131072;

  Biases bs;
  bs.p[0] = q_b; bs.p[1] = k_b; bs.p[2] = v_b;

  dim3 blk(256);
  cvt_all<<<dim3(2048, 7), blk, 0, stream>>>(ca);
  proj3_kernel<<<dim3(8, 64, 3), blk, 0, stream>>>(Qb, Wq, bs, Qp);
  flash_kernel<<<dim3(128, 8), blk, 0, stream>>>(Qp, Kp, Vt, attn, Ctx);
  outb_kernel<<<dim3(8, 64), blk, 0, stream>>>(Ctx, Wo, out_b, outp);
}